// Round 6
// baseline (3974.231 us; speedup 1.0000x reference)
//
#include <hip/hip_runtime.h>

// Problem constants (from reference)
#define NN 50000      // nodes
#define NE 300000     // edges
#define FEA 64        // edge feature dim
#define HD 256        // hidden
#define NG 256        // graphs
#define NL 4          // layers
#define OD 128        // out dim
#define NCH 8         // edge chunks
#define ECH (NE / NCH)
#define SP 72         // LDS row stride in u16 (64 + 8 pad: 16B-aligned, 2-way bank alias = free)

typedef unsigned short u16;
typedef unsigned int u32;
typedef __attribute__((ext_vector_type(8))) short short8;
typedef __attribute__((ext_vector_type(4))) float f32x4;

__device__ __forceinline__ float bf2f(u16 u) {
    union { u32 i; float f; } v; v.i = ((u32)u) << 16; return v.f;
}
__device__ __forceinline__ u16 f2bf(float f) {
    union { float f; u32 i; } v; v.f = f;
    u32 b = v.i;
    u32 r = (b + 0x7FFFu + ((b >> 16) & 1u)) >> 16;
    return (u16)r;
}

// ---------------------------------------------------------------------------
// Tiled MFMA GEMM: C[M,256] = epi(A[M,K] @ (Bhi+Blo)[256,K]^T + bias)
// Split-bf16 weights: B = Bhi + Blo gives ~fp32-accurate weights (systematic
// error is what survives graph pooling); activations stay single-bf16.
// Tile 128x128, BK=64, 4 waves (2x2), 4x4 16x16x32 frags, 2 MFMAs per pair.
// EPI 0: relu -> bf16 store to C
// EPI 1: e + x[src] -> relu -> atomicAdd aggr[dst]   (GINE message+aggregate)
// EPI 3: relu -> bf16 store + BN sum/sumsq atomics
// ---------------------------------------------------------------------------
template<int EPI>
__global__ __launch_bounds__(256, 2) void gemm_k(
    const u16* __restrict__ A, const u16* __restrict__ Bt,
    const u16* __restrict__ Btl,
    const float* __restrict__ bias, int M, int K,
    u16* __restrict__ C,
    const int* __restrict__ srcI, const int* __restrict__ dstI,
    const u16* __restrict__ xb, float* __restrict__ aggr,
    float* __restrict__ bns, float* __restrict__ bnq)
{
    __shared__ __align__(16) u16 ldsA[128 * SP];
    __shared__ __align__(16) u16 ldsB[128 * SP];
    __shared__ __align__(16) u16 ldsBl[128 * SP];
    const int tid = threadIdx.x;
    const int lane = tid & 63;
    const int w = tid >> 6;
    const int wm = w & 1, wn = w >> 1;
    const int q = lane >> 4, c15 = lane & 15;
    const int m0 = blockIdx.x * 128;
    const int n0 = blockIdx.y * 128;

    f32x4 acc[4][4];
#pragma unroll
    for (int i = 0; i < 4; ++i)
#pragma unroll
        for (int j = 0; j < 4; ++j) acc[i][j] = (f32x4)0.0f;

    for (int k0 = 0; k0 < K; k0 += 64) {
        // stage A, Bhi, Blo tiles: 1024 16B-blocks each; thread t does 4 of each
#pragma unroll
        for (int it = 0; it < 4; ++it) {
            const int i = it * 256 + tid;     // 0..1023
            const int m = i >> 3;             // tile row 0..127
            const int kb = i & 7;             // 16B block in row
            int rowA = m0 + m; if (rowA > M - 1) rowA = M - 1;   // clamp, masked later
            *(short8*)&ldsA[m * SP + kb * 8] =
                *(const short8*)(A + (size_t)rowA * K + k0 + kb * 8);
            *(short8*)&ldsB[m * SP + kb * 8] =
                *(const short8*)(Bt + (size_t)(n0 + m) * K + k0 + kb * 8);
            *(short8*)&ldsBl[m * SP + kb * 8] =
                *(const short8*)(Btl + (size_t)(n0 + m) * K + k0 + kb * 8);
        }
        __syncthreads();
#pragma unroll
        for (int s = 0; s < 2; ++s) {
            short8 af[4], bh[4], bl[4];
#pragma unroll
            for (int t = 0; t < 4; ++t) {
                const int kga = s * 4 + q;               // 16B block index in row
                const int mm = wm * 64 + t * 16 + c15;
                af[t] = *(const short8*)&ldsA[mm * SP + kga * 8];
                const int nn = wn * 64 + t * 16 + c15;
                bh[t] = *(const short8*)&ldsB[nn * SP + kga * 8];
                bl[t] = *(const short8*)&ldsBl[nn * SP + kga * 8];
            }
#pragma unroll
            for (int tm = 0; tm < 4; ++tm)
#pragma unroll
                for (int tn = 0; tn < 4; ++tn) {
                    acc[tm][tn] = __builtin_amdgcn_mfma_f32_16x16x32_bf16(
                        af[tm], bh[tn], acc[tm][tn], 0, 0, 0);
                    acc[tm][tn] = __builtin_amdgcn_mfma_f32_16x16x32_bf16(
                        af[tm], bl[tn], acc[tm][tn], 0, 0, 0);
                }
        }
        __syncthreads();
    }

    float biasf[4];
#pragma unroll
    for (int tn = 0; tn < 4; ++tn)
        biasf[tn] = bias[n0 + wn * 64 + tn * 16 + c15];

    if (EPI == 1) {
#pragma unroll
        for (int tm = 0; tm < 4; ++tm) {
#pragma unroll
            for (int r = 0; r < 4; ++r) {
                const int erow = m0 + wm * 64 + tm * 16 + q * 4 + r;
                if (erow < M) {
                    const int sn = srcI[erow], dn = dstI[erow];
                    const u16* xr = xb + (size_t)sn * HD;
                    float* ar = aggr + (size_t)dn * HD;
#pragma unroll
                    for (int tn = 0; tn < 4; ++tn) {
                        const int col = n0 + wn * 64 + tn * 16 + c15;
                        const float msg = acc[tm][tn][r] + biasf[tn] + bf2f(xr[col]);
                        if (msg > 0.0f) unsafeAtomicAdd(&ar[col], msg);
                    }
                }
            }
        }
    } else {
        float ps[4] = {0, 0, 0, 0}, pq[4] = {0, 0, 0, 0};
#pragma unroll
        for (int tm = 0; tm < 4; ++tm) {
#pragma unroll
            for (int r = 0; r < 4; ++r) {
                const int grow = m0 + wm * 64 + tm * 16 + q * 4 + r;
                if (grow < M) {
#pragma unroll
                    for (int tn = 0; tn < 4; ++tn) {
                        const int col = n0 + wn * 64 + tn * 16 + c15;
                        float v = acc[tm][tn][r] + biasf[tn];
                        v = v > 0.0f ? v : 0.0f;  // relu
                        C[(size_t)grow * HD + col] = f2bf(v);
                        if (EPI == 3) { ps[tn] += v; pq[tn] += v * v; }
                    }
                }
            }
        }
        if (EPI == 3) {
#pragma unroll
            for (int tn = 0; tn < 4; ++tn) {
                float s = ps[tn], sq = pq[tn];
                s += __shfl_down(s, 32, 64);  sq += __shfl_down(sq, 32, 64);
                s += __shfl_down(s, 16, 64);  sq += __shfl_down(sq, 16, 64);
                if (q == 0) {
                    const int col = n0 + wn * 64 + tn * 16 + c15;
                    unsafeAtomicAdd(&bns[col], s);
                    unsafeAtomicAdd(&bnq[col], sq);
                }
            }
        }
    }
}

// --------------------------- small helper kernels ---------------------------

// fp32 [L,K,N] -> split bf16 transposed [L,N,K] (hi + lo)
__global__ void transpose_k(const float* __restrict__ in, u16* __restrict__ oh,
                            u16* __restrict__ ol, int Kw, int Nw) {
    int i = blockIdx.x * blockDim.x + threadIdx.x;
    int tot = NL * Kw * Nw;
    if (i < tot) {
        int l = i / (Kw * Nw), rem = i % (Kw * Nw);
        int k = rem / Nw, n = rem % Nw;
        float wv = in[i];
        u16 hi = f2bf(wv);
        float lo = wv - bf2f(hi);
        size_t idx = (size_t)l * Kw * Nw + (size_t)n * Kw + k;
        oh[idx] = hi;
        ol[idx] = f2bf(lo);
    }
}

// fp32 -> bf16 elementwise (x init, edge-attr chunk)
__global__ void cvt_k(const float* __restrict__ in, u16* __restrict__ outb, int tot) {
    int i = blockIdx.x * blockDim.x + threadIdx.x;
    if (i < tot) outb[i] = f2bf(in[i]);
}

__global__ void zero_layer_k(float* __restrict__ aggr, float* __restrict__ bns,
                             float* __restrict__ bnq) {
    int i = blockIdx.x * blockDim.x + threadIdx.x;
    if (i < NN * HD) aggr[i] = 0.0f;
    if (i < HD) { bns[i] = 0.0f; bnq[i] = 0.0f; }
}

__global__ void h0_k(const u16* __restrict__ xb, const float* __restrict__ aggr,
                     u16* __restrict__ h0, const float* __restrict__ epsv, int l) {
    int i = blockIdx.x * blockDim.x + threadIdx.x;
    if (i < NN * HD) {
        float e1 = 1.0f + epsv[l];
        h0[i] = f2bf(e1 * bf2f(xb[i]) + aggr[i]);
    }
}

__global__ void bnfin_k(const float* __restrict__ bns, const float* __restrict__ bnq,
                        const float* __restrict__ gamma, const float* __restrict__ beta,
                        int l, float* __restrict__ ab) {
    int c = threadIdx.x;
    float mu = bns[c] * (1.0f / (float)NN);
    float var = bnq[c] * (1.0f / (float)NN) - mu * mu;
    if (var < 0.0f) var = 0.0f;
    float a = gamma[l * HD + c] * rsqrtf(var + 1e-5f);
    float b = beta[l * HD + c] - mu * a;
    ab[c] = a; ab[HD + c] = b;
}

__global__ void bnapply_k(const u16* __restrict__ hb, const float* __restrict__ ab,
                          u16* __restrict__ xb) {
    int i = blockIdx.x * blockDim.x + threadIdx.x;
    if (i < NN * HD) {
        int c = i & (HD - 1);
        xb[i] = f2bf(ab[c] * bf2f(hb[i]) + ab[HD + c]);
    }
}

__global__ void zcnt_k(int* __restrict__ cnts) {
    if (threadIdx.x < NG) cnts[threadIdx.x] = 0;
}

__global__ void count_k(const int* __restrict__ batch, int* __restrict__ cnts) {
    int i = blockIdx.x * blockDim.x + threadIdx.x;
    if (i < NN) atomicAdd(&cnts[batch[i]], 1);
}

__global__ void offs_k(const int* __restrict__ cnts, int* __restrict__ offs) {
    if (threadIdx.x == 0) {
        int a = 0;
        for (int g = 0; g < NG; ++g) { offs[g] = a; a += cnts[g]; }
        offs[NG] = a;
    }
}

// mean-pool current layer's xb (bf16) into its fp32 slice of pooled [G, L*H]
__global__ void pool_layer_k(const u16* __restrict__ xb, const int* __restrict__ offs,
                             float* __restrict__ pooled, int l) {
    int g = blockIdx.x, t = threadIdx.x;
    int lo = offs[g], hi = offs[g + 1];
    float s = 0.0f;
    for (int n = lo; n < hi; ++n) s += bf2f(xb[(size_t)n * HD + t]);
    int c = hi - lo; if (c < 1) c = 1;
    pooled[(size_t)g * (NL * HD) + l * HD + t] = s / (float)c;
}

__global__ void fc_k(const float* __restrict__ pooled,
                     const float* __restrict__ W1, const float* __restrict__ b1,
                     const float* __restrict__ W4, const float* __restrict__ b4,
                     float* __restrict__ out) {
    __shared__ float pl[NL * HD];
    __shared__ float hm[HD];
    int g = blockIdx.x, t = threadIdx.x;
#pragma unroll
    for (int j = 0; j < 4; ++j) pl[t + j * 256] = pooled[(size_t)g * 1024 + t + j * 256];
    __syncthreads();
    float a = b1[t];
    for (int k = 0; k < 1024; ++k) a += pl[k] * W1[k * 256 + t];
    hm[t] = a > 0.0f ? a : 0.0f;
    __syncthreads();
    if (t < OD) {
        float o = b4[t];
        for (int k = 0; k < 256; ++k) o += hm[k] * W4[k * OD + t];
        out[g * OD + t] = o;
    }
}

// ---------------------------------------------------------------------------

extern "C" void kernel_launch(void* const* d_in, const int* in_sizes, int n_in,
                              void* d_out, int out_size, void* d_ws, size_t ws_size,
                              hipStream_t stream) {
    const float* x_in  = (const float*)d_in[0];
    const int*   eidx  = (const int*)d_in[1];
    const float* eattr = (const float*)d_in[2];
    const int*   batch = (const int*)d_in[3];
    const float* bW1   = (const float*)d_in[4];
    const float* bb1   = (const float*)d_in[5];
    const float* bW2   = (const float*)d_in[6];
    const float* bb2   = (const float*)d_in[7];
    const float* mW1   = (const float*)d_in[8];
    const float* mb1   = (const float*)d_in[9];
    const float* mW2   = (const float*)d_in[10];
    const float* mb2   = (const float*)d_in[11];
    const float* epsv  = (const float*)d_in[12];
    const float* gamma = (const float*)d_in[13];
    const float* beta  = (const float*)d_in[14];
    const float* fc1W  = (const float*)d_in[15];
    const float* fc1b  = (const float*)d_in[16];
    const float* fc4W  = (const float*)d_in[17];
    const float* fc4b  = (const float*)d_in[18];
    float* out = (float*)d_out;
    (void)in_sizes; (void)n_in; (void)out_size; (void)ws_size;

    // ---- workspace carve (~133 MB total; round-4's ~156 MB ran without fault) ----
    size_t off = 0;
    auto alloc = [&](size_t bytes) -> char* {
        char* r = (char*)d_ws + off;
        off = (off + bytes + 255) & ~(size_t)255;
        return r;
    };
    u16*   xb   = (u16*)alloc((size_t)NN * HD * 2);    // 25.6 MB node feats, bf16
    float* aggr = (float*)alloc((size_t)NN * HD * 4);  // 51.2 MB scatter acc, fp32
    u16*   h0hb = (u16*)alloc((size_t)NN * HD * 2);    // 25.6 MB h0, reused as hb
    u16*   W1t  = (u16*)alloc((size_t)NL * FEA * HD * 2);
    u16*   W1tl = (u16*)alloc((size_t)NL * FEA * HD * 2);
    u16*   W2t  = (u16*)alloc((size_t)NL * HD * HD * 2);
    u16*   W2tl = (u16*)alloc((size_t)NL * HD * HD * 2);
    u16*   M1t  = (u16*)alloc((size_t)NL * HD * HD * 2);
    u16*   M1tl = (u16*)alloc((size_t)NL * HD * HD * 2);
    u16*   M2t  = (u16*)alloc((size_t)NL * HD * HD * 2);
    u16*   M2tl = (u16*)alloc((size_t)NL * HD * HD * 2);
    float* bns  = (float*)alloc(HD * 4);
    float* bnq  = (float*)alloc(HD * 4);
    float* ab   = (float*)alloc(2 * HD * 4);
    int*   cnts = (int*)alloc(NG * 4);
    int*   offs = (int*)alloc((NG + 1) * 4);
    float* pooled = (float*)alloc((size_t)NG * NL * HD * 4);
    // union region (25.6 MB): node phase T2 | edge phase {T1 19.2 MB + ebc 4.8 MB}
    u16* T2  = (u16*)alloc((size_t)NN * HD * 2);
    u16* T1  = T2;
    u16* ebc = T2 + (size_t)ECH * HD;                  // bf16 edge-attr chunk

    const int NEL = NN * HD;              // 12.8M elements
    const int EB = (NEL + 255) / 256;     // elementwise grid

    // weights: fp32 -> split bf16 (hi+lo), transposed to [N,K]
    transpose_k<<<(NL * FEA * HD + 255) / 256, 256, 0, stream>>>(bW1, W1t, W1tl, FEA, HD);
    transpose_k<<<(NL * HD * HD + 255) / 256, 256, 0, stream>>>(bW2, W2t, W2tl, HD, HD);
    transpose_k<<<(NL * HD * HD + 255) / 256, 256, 0, stream>>>(mW1, M1t, M1tl, HD, HD);
    transpose_k<<<(NL * HD * HD + 255) / 256, 256, 0, stream>>>(mW2, M2t, M2tl, HD, HD);

    cvt_k<<<EB, 256, 0, stream>>>(x_in, xb, NEL);
    zcnt_k<<<1, 256, 0, stream>>>(cnts);
    count_k<<<(NN + 255) / 256, 256, 0, stream>>>(batch, cnts);
    offs_k<<<1, 64, 0, stream>>>(cnts, offs);

    for (int l = 0; l < NL; ++l) {
        zero_layer_k<<<EB, 256, 0, stream>>>(aggr, bns, bnq);
        // edge path: cvt chunk -> bond GEMM1 -> bond GEMM2 + fused message/scatter
        for (int c = 0; c < NCH; ++c) {
            const int e0 = c * ECH;
            cvt_k<<<(ECH * FEA + 255) / 256, 256, 0, stream>>>(
                eattr + (size_t)e0 * FEA, ebc, ECH * FEA);
            dim3 g1((ECH + 127) / 128, 2);
            gemm_k<0><<<g1, 256, 0, stream>>>(
                ebc, W1t + (size_t)l * FEA * HD, W1tl + (size_t)l * FEA * HD,
                bb1 + l * HD, ECH, FEA, T1,
                nullptr, nullptr, nullptr, nullptr, nullptr, nullptr);
            gemm_k<1><<<g1, 256, 0, stream>>>(
                T1, W2t + (size_t)l * HD * HD, W2tl + (size_t)l * HD * HD,
                bb2 + l * HD, ECH, HD, nullptr,
                eidx + e0, eidx + NE + e0, xb, aggr, nullptr, nullptr);
        }
        h0_k<<<EB, 256, 0, stream>>>(xb, aggr, h0hb, epsv, l);
        dim3 g2((NN + 127) / 128, 2);
        gemm_k<0><<<g2, 256, 0, stream>>>(
            h0hb, M1t + (size_t)l * HD * HD, M1tl + (size_t)l * HD * HD,
            mb1 + l * HD, NN, HD, T2,
            nullptr, nullptr, nullptr, nullptr, nullptr, nullptr);
        gemm_k<3><<<g2, 256, 0, stream>>>(
            T2, M2t + (size_t)l * HD * HD, M2tl + (size_t)l * HD * HD,
            mb2 + l * HD, NN, HD, h0hb,
            nullptr, nullptr, nullptr, nullptr, bns, bnq);
        bnfin_k<<<1, HD, 0, stream>>>(bns, bnq, gamma, beta, l, ab);
        bnapply_k<<<EB, 256, 0, stream>>>(h0hb, ab, xb);
        pool_layer_k<<<NG, HD, 0, stream>>>(xb, offs, pooled, l);
    }
    fc_k<<<NG, 256, 0, stream>>>(pooled, fc1W, fc1b, fc4W, fc4b, out);
}

// Round 7
// 3837.336 us; speedup vs baseline: 1.0357x; 1.0357x over previous
//
#include <hip/hip_runtime.h>

// Problem constants (from reference)
#define NN 50000      // nodes
#define NE 300000     // edges
#define FEA 64        // edge feature dim
#define HD 256        // hidden
#define NG 256        // graphs
#define NL 4          // layers
#define OD 128        // out dim
#define NCH 8         // edge chunks
#define ECH (NE / NCH)
#define SP 72         // LDS row stride in u16 (64 + 8 pad: 16B-aligned, 2-way bank alias = free)

typedef unsigned short u16;
typedef unsigned int u32;
typedef __attribute__((ext_vector_type(8))) short short8;
typedef __attribute__((ext_vector_type(4))) float f32x4;

__device__ __forceinline__ float bf2f(u16 u) {
    union { u32 i; float f; } v; v.i = ((u32)u) << 16; return v.f;
}
__device__ __forceinline__ u16 f2bf(float f) {
    union { float f; u32 i; } v; v.f = f;
    u32 b = v.i;
    u32 r = (b + 0x7FFFu + ((b >> 16) & 1u)) >> 16;
    return (u16)r;
}

// ---------------------------------------------------------------------------
// Tiled MFMA GEMM: C[M,256] = epi(A[M,K] @ (Bhi+Blo)[256,K]^T + bias)
// Split-bf16 weights (systematic error is what survives graph pooling).
// Tile 128x128, BK=64, 4 waves (2x2), 4x4 16x16x32 frags, 2 MFMAs per pair.
// EPI 0: relu -> bf16 store to C
// EPI 1: e + x[src] -> relu -> run-dedup atomicAdd aggr[dst] (edges SORTED by dst)
// EPI 3: relu -> bf16 store + BN sum/sumsq atomics
// ---------------------------------------------------------------------------
template<int EPI>
__global__ __launch_bounds__(256, 2) void gemm_k(
    const u16* __restrict__ A, const u16* __restrict__ Bt,
    const u16* __restrict__ Btl,
    const float* __restrict__ bias, int M, int K,
    u16* __restrict__ C,
    const int* __restrict__ srcI, const int* __restrict__ dstI,
    const u16* __restrict__ xb, float* __restrict__ aggr,
    float* __restrict__ bns, float* __restrict__ bnq)
{
    __shared__ __align__(16) u16 ldsA[128 * SP];
    __shared__ __align__(16) u16 ldsB[128 * SP];
    __shared__ __align__(16) u16 ldsBl[128 * SP];
    const int tid = threadIdx.x;
    const int lane = tid & 63;
    const int w = tid >> 6;
    const int wm = w & 1, wn = w >> 1;
    const int q = lane >> 4, c15 = lane & 15;
    const int m0 = blockIdx.x * 128;
    const int n0 = blockIdx.y * 128;

    f32x4 acc[4][4];
#pragma unroll
    for (int i = 0; i < 4; ++i)
#pragma unroll
        for (int j = 0; j < 4; ++j) acc[i][j] = (f32x4)0.0f;

    for (int k0 = 0; k0 < K; k0 += 64) {
        // stage A, Bhi, Blo tiles: 1024 16B-blocks each; thread t does 4 of each
#pragma unroll
        for (int it = 0; it < 4; ++it) {
            const int i = it * 256 + tid;     // 0..1023
            const int m = i >> 3;             // tile row 0..127
            const int kb = i & 7;             // 16B block in row
            int rowA = m0 + m; if (rowA > M - 1) rowA = M - 1;   // clamp, masked later
            *(short8*)&ldsA[m * SP + kb * 8] =
                *(const short8*)(A + (size_t)rowA * K + k0 + kb * 8);
            *(short8*)&ldsB[m * SP + kb * 8] =
                *(const short8*)(Bt + (size_t)(n0 + m) * K + k0 + kb * 8);
            *(short8*)&ldsBl[m * SP + kb * 8] =
                *(const short8*)(Btl + (size_t)(n0 + m) * K + k0 + kb * 8);
        }
        __syncthreads();
#pragma unroll
        for (int s = 0; s < 2; ++s) {
            short8 af[4], bh[4], bl[4];
#pragma unroll
            for (int t = 0; t < 4; ++t) {
                const int kga = s * 4 + q;               // 16B block index in row
                const int mm = wm * 64 + t * 16 + c15;
                af[t] = *(const short8*)&ldsA[mm * SP + kga * 8];
                const int nn = wn * 64 + t * 16 + c15;
                bh[t] = *(const short8*)&ldsB[nn * SP + kga * 8];
                bl[t] = *(const short8*)&ldsBl[nn * SP + kga * 8];
            }
#pragma unroll
            for (int tm = 0; tm < 4; ++tm)
#pragma unroll
                for (int tn = 0; tn < 4; ++tn) {
                    acc[tm][tn] = __builtin_amdgcn_mfma_f32_16x16x32_bf16(
                        af[tm], bh[tn], acc[tm][tn], 0, 0, 0);
                    acc[tm][tn] = __builtin_amdgcn_mfma_f32_16x16x32_bf16(
                        af[tm], bl[tn], acc[tm][tn], 0, 0, 0);
                }
        }
        __syncthreads();
    }

    float biasf[4];
#pragma unroll
    for (int tn = 0; tn < 4; ++tn)
        biasf[tn] = bias[n0 + wn * 64 + tn * 16 + c15];

    if (EPI == 1) {
        // edges are sorted by dst; each lane owns 4 consecutive edges -> run-dedup
#pragma unroll
        for (int tm = 0; tm < 4; ++tm) {
            const int base = m0 + wm * 64 + tm * 16 + q * 4;
            int sn[4], dn[4];
            bool val[4];
#pragma unroll
            for (int r = 0; r < 4; ++r) {
                const int erow = base + r;
                val[r] = erow < M;
                const int er = val[r] ? erow : (M - 1);
                sn[r] = srcI[er];
                dn[r] = dstI[er];
            }
#pragma unroll
            for (int tn = 0; tn < 4; ++tn) {
                const int col = n0 + wn * 64 + tn * 16 + c15;
                float accv = 0.0f;
                int cur = -1;
#pragma unroll
                for (int r = 0; r < 4; ++r) {
                    if (val[r]) {
                        float msg = acc[tm][tn][r] + biasf[tn]
                                  + bf2f(xb[(size_t)sn[r] * HD + col]);
                        msg = msg > 0.0f ? msg : 0.0f;
                        if (dn[r] != cur) {
                            if (cur >= 0 && accv > 0.0f)
                                unsafeAtomicAdd(&aggr[(size_t)cur * HD + col], accv);
                            cur = dn[r];
                            accv = 0.0f;
                        }
                        accv += msg;
                    }
                }
                if (cur >= 0 && accv > 0.0f)
                    unsafeAtomicAdd(&aggr[(size_t)cur * HD + col], accv);
            }
        }
    } else {
        float ps[4] = {0, 0, 0, 0}, pq[4] = {0, 0, 0, 0};
#pragma unroll
        for (int tm = 0; tm < 4; ++tm) {
#pragma unroll
            for (int r = 0; r < 4; ++r) {
                const int grow = m0 + wm * 64 + tm * 16 + q * 4 + r;
                if (grow < M) {
#pragma unroll
                    for (int tn = 0; tn < 4; ++tn) {
                        const int col = n0 + wn * 64 + tn * 16 + c15;
                        float v = acc[tm][tn][r] + biasf[tn];
                        v = v > 0.0f ? v : 0.0f;  // relu
                        C[(size_t)grow * HD + col] = f2bf(v);
                        if (EPI == 3) { ps[tn] += v; pq[tn] += v * v; }
                    }
                }
            }
        }
        if (EPI == 3) {
#pragma unroll
            for (int tn = 0; tn < 4; ++tn) {
                float s = ps[tn], sq = pq[tn];
                s += __shfl_down(s, 32, 64);  sq += __shfl_down(sq, 32, 64);
                s += __shfl_down(s, 16, 64);  sq += __shfl_down(sq, 16, 64);
                if (q == 0) {
                    const int col = n0 + wn * 64 + tn * 16 + c15;
                    unsafeAtomicAdd(&bns[col], s);
                    unsafeAtomicAdd(&bnq[col], sq);
                }
            }
        }
    }
}

// --------------------------- small helper kernels ---------------------------

// fp32 [L,K,N] -> split bf16 transposed [L,N,K] (hi + lo)
__global__ void transpose_k(const float* __restrict__ in, u16* __restrict__ oh,
                            u16* __restrict__ ol, int Kw, int Nw) {
    int i = blockIdx.x * blockDim.x + threadIdx.x;
    int tot = NL * Kw * Nw;
    if (i < tot) {
        int l = i / (Kw * Nw), rem = i % (Kw * Nw);
        int k = rem / Nw, n = rem % Nw;
        float wv = in[i];
        u16 hi = f2bf(wv);
        float lo = wv - bf2f(hi);
        size_t idx = (size_t)l * Kw * Nw + (size_t)n * Kw + k;
        oh[idx] = hi;
        ol[idx] = f2bf(lo);
    }
}

// fp32 -> bf16 elementwise
__global__ void cvt_k(const float* __restrict__ in, u16* __restrict__ outb, int tot) {
    int i = blockIdx.x * blockDim.x + threadIdx.x;
    if (i < tot) outb[i] = f2bf(in[i]);
}

// gather rows of eattr by perm, fp32 -> bf16  (row = sorted edge index)
__global__ void cvtg_k(const float* __restrict__ eattr, const int* __restrict__ perm,
                       int e0, u16* __restrict__ outb) {
    int i = blockIdx.x * blockDim.x + threadIdx.x;
    if (i < ECH * FEA) {
        int row = i >> 6, k = i & 63;
        outb[i] = f2bf(eattr[(size_t)perm[e0 + row] * FEA + k]);
    }
}

__global__ void zero_layer_k(float* __restrict__ aggr, float* __restrict__ bns,
                             float* __restrict__ bnq) {
    int i = blockIdx.x * blockDim.x + threadIdx.x;
    if (i < NN * HD) aggr[i] = 0.0f;
    if (i < HD) { bns[i] = 0.0f; bnq[i] = 0.0f; }
}

__global__ void h0_k(const u16* __restrict__ xb, const float* __restrict__ aggr,
                     u16* __restrict__ h0, const float* __restrict__ epsv, int l) {
    int i = blockIdx.x * blockDim.x + threadIdx.x;
    if (i < NN * HD) {
        float e1 = 1.0f + epsv[l];
        h0[i] = f2bf(e1 * bf2f(xb[i]) + aggr[i]);
    }
}

__global__ void bnfin_k(const float* __restrict__ bns, const float* __restrict__ bnq,
                        const float* __restrict__ gamma, const float* __restrict__ beta,
                        int l, float* __restrict__ ab) {
    int c = threadIdx.x;
    float mu = bns[c] * (1.0f / (float)NN);
    float var = bnq[c] * (1.0f / (float)NN) - mu * mu;
    if (var < 0.0f) var = 0.0f;
    float a = gamma[l * HD + c] * rsqrtf(var + 1e-5f);
    float b = beta[l * HD + c] - mu * a;
    ab[c] = a; ab[HD + c] = b;
}

__global__ void bnapply_k(const u16* __restrict__ hb, const float* __restrict__ ab,
                          u16* __restrict__ xb) {
    int i = blockIdx.x * blockDim.x + threadIdx.x;
    if (i < NN * HD) {
        int c = i & (HD - 1);
        xb[i] = f2bf(ab[c] * bf2f(hb[i]) + ab[HD + c]);
    }
}

// ---- edge counting-sort by dst ----

__global__ void zeroi_k(int* __restrict__ a, int n) {
    int i = blockIdx.x * blockDim.x + threadIdx.x;
    if (i < n) a[i] = 0;
}

__global__ void hist_k(const int* __restrict__ dst, int* __restrict__ hist) {
    int e = blockIdx.x * blockDim.x + threadIdx.x;
    if (e < NE) atomicAdd(&hist[dst[e]], 1);
}

// single-block exclusive scan over NN bins -> rowptr[NN+1]
__global__ void scan_k(const int* __restrict__ hist, int* __restrict__ rowptr) {
    __shared__ int tot[256];
    const int t = threadIdx.x;
    const int per = (NN + 255) / 256;
    const int lo = t * per, hi = min(lo + per, NN);
    int s = 0;
    for (int i = lo; i < hi; ++i) s += hist[i];
    tot[t] = s;
    __syncthreads();
    if (t == 0) {
        int a = 0;
        for (int j = 0; j < 256; ++j) { int v = tot[j]; tot[j] = a; a += v; }
    }
    __syncthreads();
    int a = tot[t];
    for (int i = lo; i < hi; ++i) { rowptr[i] = a; a += hist[i]; }
    if (hi == NN) rowptr[NN] = a;
}

__global__ void copyi_k(const int* __restrict__ src, int* __restrict__ dst, int n) {
    int i = blockIdx.x * blockDim.x + threadIdx.x;
    if (i < n) dst[i] = src[i];
}

__global__ void scatter_k(const int* __restrict__ dst, int* __restrict__ next,
                          int* __restrict__ perm) {
    int e = blockIdx.x * blockDim.x + threadIdx.x;
    if (e < NE) {
        int p = atomicAdd(&next[dst[e]], 1);
        perm[p] = e;
    }
}

__global__ void permsd_k(const int* __restrict__ eidx, const int* __restrict__ perm,
                         int* __restrict__ srcS, int* __restrict__ dstS) {
    int i = blockIdx.x * blockDim.x + threadIdx.x;
    if (i < NE) {
        int e = perm[i];
        srcS[i] = eidx[e];
        dstS[i] = eidx[NE + e];
    }
}

// ---- graph pooling ----

__global__ void zcnt_k(int* __restrict__ cnts) {
    if (threadIdx.x < NG) cnts[threadIdx.x] = 0;
}

__global__ void count_k(const int* __restrict__ batch, int* __restrict__ cnts) {
    int i = blockIdx.x * blockDim.x + threadIdx.x;
    if (i < NN) atomicAdd(&cnts[batch[i]], 1);
}

__global__ void offs_k(const int* __restrict__ cnts, int* __restrict__ offs) {
    if (threadIdx.x == 0) {
        int a = 0;
        for (int g = 0; g < NG; ++g) { offs[g] = a; a += cnts[g]; }
        offs[NG] = a;
    }
}

__global__ void pool_layer_k(const u16* __restrict__ xb, const int* __restrict__ offs,
                             float* __restrict__ pooled, int l) {
    int g = blockIdx.x, t = threadIdx.x;
    int lo = offs[g], hi = offs[g + 1];
    float s = 0.0f;
    for (int n = lo; n < hi; ++n) s += bf2f(xb[(size_t)n * HD + t]);
    int c = hi - lo; if (c < 1) c = 1;
    pooled[(size_t)g * (NL * HD) + l * HD + t] = s / (float)c;
}

__global__ void fc_k(const float* __restrict__ pooled,
                     const float* __restrict__ W1, const float* __restrict__ b1,
                     const float* __restrict__ W4, const float* __restrict__ b4,
                     float* __restrict__ out) {
    __shared__ float pl[NL * HD];
    __shared__ float hm[HD];
    int g = blockIdx.x, t = threadIdx.x;
#pragma unroll
    for (int j = 0; j < 4; ++j) pl[t + j * 256] = pooled[(size_t)g * 1024 + t + j * 256];
    __syncthreads();
    float a = b1[t];
    for (int k = 0; k < 1024; ++k) a += pl[k] * W1[k * 256 + t];
    hm[t] = a > 0.0f ? a : 0.0f;
    __syncthreads();
    if (t < OD) {
        float o = b4[t];
        for (int k = 0; k < 256; ++k) o += hm[k] * W4[k * OD + t];
        out[g * OD + t] = o;
    }
}

// ---------------------------------------------------------------------------

extern "C" void kernel_launch(void* const* d_in, const int* in_sizes, int n_in,
                              void* d_out, int out_size, void* d_ws, size_t ws_size,
                              hipStream_t stream) {
    const float* x_in  = (const float*)d_in[0];
    const int*   eidx  = (const int*)d_in[1];
    const float* eattr = (const float*)d_in[2];
    const int*   batch = (const int*)d_in[3];
    const float* bW1   = (const float*)d_in[4];
    const float* bb1   = (const float*)d_in[5];
    const float* bW2   = (const float*)d_in[6];
    const float* bb2   = (const float*)d_in[7];
    const float* mW1   = (const float*)d_in[8];
    const float* mb1   = (const float*)d_in[9];
    const float* mW2   = (const float*)d_in[10];
    const float* mb2   = (const float*)d_in[11];
    const float* epsv  = (const float*)d_in[12];
    const float* gamma = (const float*)d_in[13];
    const float* beta  = (const float*)d_in[14];
    const float* fc1W  = (const float*)d_in[15];
    const float* fc1b  = (const float*)d_in[16];
    const float* fc4W  = (const float*)d_in[17];
    const float* fc4b  = (const float*)d_in[18];
    float* out = (float*)d_out;
    (void)in_sizes; (void)n_in; (void)out_size; (void)ws_size;

    // ---- workspace carve (~137 MB; round-4's ~156 MB ran without fault) ----
    size_t off = 0;
    auto alloc = [&](size_t bytes) -> char* {
        char* r = (char*)d_ws + off;
        off = (off + bytes + 255) & ~(size_t)255;
        return r;
    };
    u16*   xb   = (u16*)alloc((size_t)NN * HD * 2);    // 25.6 MB node feats, bf16
    float* aggr = (float*)alloc((size_t)NN * HD * 4);  // 51.2 MB scatter acc, fp32
    u16*   h0hb = (u16*)alloc((size_t)NN * HD * 2);    // 25.6 MB h0, reused as hb
    u16*   W1t  = (u16*)alloc((size_t)NL * FEA * HD * 2);
    u16*   W1tl = (u16*)alloc((size_t)NL * FEA * HD * 2);
    u16*   W2t  = (u16*)alloc((size_t)NL * HD * HD * 2);
    u16*   W2tl = (u16*)alloc((size_t)NL * HD * HD * 2);
    u16*   M1t  = (u16*)alloc((size_t)NL * HD * HD * 2);
    u16*   M1tl = (u16*)alloc((size_t)NL * HD * HD * 2);
    u16*   M2t  = (u16*)alloc((size_t)NL * HD * HD * 2);
    u16*   M2tl = (u16*)alloc((size_t)NL * HD * HD * 2);
    float* bns  = (float*)alloc(HD * 4);
    float* bnq  = (float*)alloc(HD * 4);
    float* ab   = (float*)alloc(2 * HD * 4);
    int*   cnts = (int*)alloc(NG * 4);
    int*   offs = (int*)alloc((NG + 1) * 4);
    float* pooled = (float*)alloc((size_t)NG * NL * HD * 4);
    int*   hist  = (int*)alloc((size_t)NN * 4);        // also reused as `next`
    int*   rowptr = (int*)alloc((size_t)(NN + 1) * 4);
    int*   perm  = (int*)alloc((size_t)NE * 4);
    int*   srcS  = (int*)alloc((size_t)NE * 4);
    int*   dstS  = (int*)alloc((size_t)NE * 4);
    // union region (25.6 MB): node phase T2 | edge phase {T1 19.2 MB + ebc 4.8 MB}
    u16* T2  = (u16*)alloc((size_t)NN * HD * 2);
    u16* T1  = T2;
    u16* ebc = T2 + (size_t)ECH * HD;                  // bf16 edge-attr chunk

    const int NEL = NN * HD;              // 12.8M elements
    const int EB = (NEL + 255) / 256;     // elementwise grid
    const int NEB = (NE + 255) / 256;

    // weights: fp32 -> split bf16 (hi+lo), transposed to [N,K]
    transpose_k<<<(NL * FEA * HD + 255) / 256, 256, 0, stream>>>(bW1, W1t, W1tl, FEA, HD);
    transpose_k<<<(NL * HD * HD + 255) / 256, 256, 0, stream>>>(bW2, W2t, W2tl, HD, HD);
    transpose_k<<<(NL * HD * HD + 255) / 256, 256, 0, stream>>>(mW1, M1t, M1tl, HD, HD);
    transpose_k<<<(NL * HD * HD + 255) / 256, 256, 0, stream>>>(mW2, M2t, M2tl, HD, HD);

    cvt_k<<<EB, 256, 0, stream>>>(x_in, xb, NEL);

    // counting-sort edges by dst: hist -> scan -> scatter perm -> permuted src/dst
    zeroi_k<<<(NN + 255) / 256, 256, 0, stream>>>(hist, NN);
    hist_k<<<NEB, 256, 0, stream>>>(eidx + NE, hist);
    scan_k<<<1, 256, 0, stream>>>(hist, rowptr);
    copyi_k<<<(NN + 255) / 256, 256, 0, stream>>>(rowptr, hist, NN);   // hist = next
    scatter_k<<<NEB, 256, 0, stream>>>(eidx + NE, hist, perm);
    permsd_k<<<NEB, 256, 0, stream>>>(eidx, perm, srcS, dstS);

    zcnt_k<<<1, 256, 0, stream>>>(cnts);
    count_k<<<(NN + 255) / 256, 256, 0, stream>>>(batch, cnts);
    offs_k<<<1, 64, 0, stream>>>(cnts, offs);

    for (int l = 0; l < NL; ++l) {
        zero_layer_k<<<EB, 256, 0, stream>>>(aggr, bns, bnq);
        // edge path (sorted order): gather-cvt chunk -> bond GEMM1 -> GEMM2+scatter
        for (int c = 0; c < NCH; ++c) {
            const int e0 = c * ECH;
            cvtg_k<<<(ECH * FEA + 255) / 256, 256, 0, stream>>>(eattr, perm, e0, ebc);
            dim3 g1((ECH + 127) / 128, 2);
            gemm_k<0><<<g1, 256, 0, stream>>>(
                ebc, W1t + (size_t)l * FEA * HD, W1tl + (size_t)l * FEA * HD,
                bb1 + l * HD, ECH, FEA, T1,
                nullptr, nullptr, nullptr, nullptr, nullptr, nullptr);
            gemm_k<1><<<g1, 256, 0, stream>>>(
                T1, W2t + (size_t)l * HD * HD, W2tl + (size_t)l * HD * HD,
                bb2 + l * HD, ECH, HD, nullptr,
                srcS + e0, dstS + e0, xb, aggr, nullptr, nullptr);
        }
        h0_k<<<EB, 256, 0, stream>>>(xb, aggr, h0hb, epsv, l);
        dim3 g2((NN + 127) / 128, 2);
        gemm_k<0><<<g2, 256, 0, stream>>>(
            h0hb, M1t + (size_t)l * HD * HD, M1tl + (size_t)l * HD * HD,
            mb1 + l * HD, NN, HD, T2,
            nullptr, nullptr, nullptr, nullptr, nullptr, nullptr);
        gemm_k<3><<<g2, 256, 0, stream>>>(
            T2, M2t + (size_t)l * HD * HD, M2tl + (size_t)l * HD * HD,
            mb2 + l * HD, NN, HD, h0hb,
            nullptr, nullptr, nullptr, nullptr, bns, bnq);
        bnfin_k<<<1, HD, 0, stream>>>(bns, bnq, gamma, beta, l, ab);
        bnapply_k<<<EB, 256, 0, stream>>>(h0hb, ab, xb);
        pool_layer_k<<<NG, HD, 0, stream>>>(xb, offs, pooled, l);
    }
    fc_k<<<NG, 256, 0, stream>>>(pooled, fc1W, fc1b, fc4W, fc4b, out);
}